// Round 7
// baseline (640.991 us; speedup 1.0000x reference)
//
#include <hip/hip_runtime.h>

#define N_ 32768
#define K_ 4096
#define NC_ 4
#define D_ 256

using floatx4 = __attribute__((ext_vector_type(4))) float;
using bf16x8  = __attribute__((ext_vector_type(8))) short;

__device__ __forceinline__ unsigned short f2bf(float f) {
  union { float f; unsigned u; } a;
  a.f = f;
  unsigned u = a.u;
  u += 0x7fffu + ((u >> 16) & 1u);  // round-to-nearest-even
  return (unsigned short)(u >> 16);
}

__device__ __forceinline__ void async_copy16(void* lds, const void* g) {
  __builtin_amdgcn_global_load_lds(
      (__attribute__((address_space(1))) void*)(g),
      (__attribute__((address_space(3))) void*)(lds),
      16, 0, 0);
}

// ---------------- prep kernels: bf16 conversion + weighted row norms --------
template <bool WRITE_BF>
__global__ void prep_x_kern(const float* __restrict__ x, const float* __restrict__ sd,
                            unsigned short* __restrict__ xb, float* __restrict__ xsq) {
  const int lane = threadIdx.x & 63;
  const int row  = blockIdx.x * 4 + (threadIdx.x >> 6);
  const float4 xv = reinterpret_cast<const float4*>(x + (size_t)row * D_)[lane];
  const float4 sv = reinterpret_cast<const float4*>(sd)[lane];
  const float i0 = 1.0f / sv.x, i1 = 1.0f / sv.y, i2 = 1.0f / sv.z, i3 = 1.0f / sv.w;
  float s = xv.x * xv.x * i0 + xv.y * xv.y * i1 + xv.z * xv.z * i2 + xv.w * xv.w * i3;
  if (WRITE_BF) {
    union { unsigned short u[4]; uint2 v; } p;
    p.u[0] = f2bf(xv.x); p.u[1] = f2bf(xv.y); p.u[2] = f2bf(xv.z); p.u[3] = f2bf(xv.w);
    reinterpret_cast<uint2*>(xb)[(size_t)row * 64 + lane] = p.v;
  }
#pragma unroll
  for (int off = 32; off > 0; off >>= 1) s += __shfl_down(s, off, 64);
  if (lane == 0) xsq[row] = s;
}

template <bool WRITE_BF>
__global__ void prep_mu_kern(const float* __restrict__ mu, const float* __restrict__ sd,
                             unsigned short* __restrict__ bb, float* __restrict__ musq) {
  const int lane = threadIdx.x & 63;
  const int row  = blockIdx.x * 4 + (threadIdx.x >> 6);
  const float4 mv = reinterpret_cast<const float4*>(mu + (size_t)row * (NC_ * D_))[lane];
  const float4 sv = reinterpret_cast<const float4*>(sd)[lane];
  const float i0 = 1.0f / sv.x, i1 = 1.0f / sv.y, i2 = 1.0f / sv.z, i3 = 1.0f / sv.w;
  float s = mv.x * mv.x * i0 + mv.y * mv.y * i1 + mv.z * mv.z * i2 + mv.w * mv.w * i3;
  if (WRITE_BF) {
    union { unsigned short u[4]; uint2 v; } p;
    p.u[0] = f2bf(mv.x * i0); p.u[1] = f2bf(mv.y * i1);
    p.u[2] = f2bf(mv.z * i2); p.u[3] = f2bf(mv.w * i3);
    reinterpret_cast<uint2*>(bb)[(size_t)row * 64 + lane] = p.v;
  }
#pragma unroll
  for (int off = 32; off > 0; off >>= 1) s += __shfl_down(s, off, 64);
  if (lane == 0) musq[row] = s;
}

// ---------------- main MFMA GEMM + XCD swizzle + coalesced PLAIN epilogue ---
// C[n,k] = expf( x·b^T - 0.5*(xsq[n] + musq[k]) ),  b = mu0 * inv_std (bf16)
// R7: single-variable test — drop the `nt` store flag. Harness fill reaches
// 6.3 TB/s with plain stores; our nt stores only reached ~3.7 TB/s.
__global__ __launch_bounds__(256, 3) void gauss_mfma(
    const unsigned short* __restrict__ xb, const unsigned short* __restrict__ bb,
    const float* __restrict__ xsq, const float* __restrict__ musq,
    float* __restrict__ out) {
  constexpr int BM = 128, BN = 128, BK = 32;
  // single contiguous buffer: K-loop uses it as As|Bs; epilogue reuses it as
  // four 4 KiB per-wave transpose patches (16 KiB total).
  __shared__ __align__(16) unsigned short smem[BM * BK + BN * BK];
  unsigned short* As = smem;
  unsigned short* Bs = smem + BM * BK;
  const int tid  = threadIdx.x;
  const int wave = tid >> 6, lane = tid & 63;
  const int wm = wave >> 1, wn = wave & 1;  // 2x2 waves, each 64x64

  const int b   = blockIdx.x;
  const int xcd = b & 7;                   // dispatch round-robins XCDs
  const int g   = b >> 3;                  // 0..1023
  const int rowT = (xcd << 5) | (g & 31);  // row-tiles banded per XCD
  const int colT = g >> 5;                 // advances every 32 blocks
  const int rowBase = rowT * BM;
  const int colBase = colT * BN;

  // staging: global_load_lds, lds dst = wave-uniform base + lane*16B
  const int srow = lane >> 2;
  const int scol = (lane & 3) * 8;
  const unsigned short* gA0 = xb + (size_t)(rowBase + wave * 16 + srow) * D_ + scol;
  const unsigned short* gA1 = gA0 + (size_t)64 * D_;
  const unsigned short* gB0 = bb + (size_t)(colBase + wave * 16 + srow) * D_ + scol;
  const unsigned short* gB1 = gB0 + (size_t)64 * D_;
  unsigned short* lA0 = &As[(wave * 16) * BK];
  unsigned short* lA1 = &As[(wave * 16 + 64) * BK];
  unsigned short* lB0 = &Bs[(wave * 16) * BK];
  unsigned short* lB1 = &Bs[(wave * 16 + 64) * BK];

  floatx4 acc[4][4] = {};
  const int fr = lane & 15;        // A: row m / B: col n
  const int fk = (lane >> 4) * 8;  // k-chunk (8 contiguous bf16 = 16B)

#pragma unroll
  for (int kt = 0; kt < D_ / BK; ++kt) {
    __syncthreads();  // everyone done reading previous tile
    async_copy16(lA0, gA0 + kt * BK);
    async_copy16(lA1, gA1 + kt * BK);
    async_copy16(lB0, gB0 + kt * BK);
    async_copy16(lB1, gB1 + kt * BK);
    __syncthreads();  // compiler drains vmcnt(0) before s_barrier
    bf16x8 af[4], bfv[4];
#pragma unroll
    for (int i = 0; i < 4; ++i)
      af[i] = *reinterpret_cast<const bf16x8*>(&As[(wm * 64 + i * 16 + fr) * BK + fk]);
#pragma unroll
    for (int j = 0; j < 4; ++j)
      bfv[j] = *reinterpret_cast<const bf16x8*>(&Bs[(wn * 64 + j * 16 + fr) * BK + fk]);
#pragma unroll
    for (int i = 0; i < 4; ++i)
#pragma unroll
      for (int j = 0; j < 4; ++j)
        acc[i][j] = __builtin_amdgcn_mfma_f32_16x16x32_bf16(af[i], bfv[j], acc[i][j], 0, 0, 0);
  }

  // ---- epilogue: exp + per-wave LDS transpose -> contiguous 1 KiB stores
  // C/D layout: col=lane&15, row=(lane>>4)*4+reg.
  __syncthreads();  // all waves done with As/Bs before reuse as patches
  float* patch = reinterpret_cast<float*>(smem) + wave * 1024;  // 16 rows x 64 cols
  const int q = lane >> 4, c = lane & 15;
  float ms[4];
#pragma unroll
  for (int j = 0; j < 4; ++j) ms[j] = musq[colBase + wn * 64 + j * 16 + c];

#pragma unroll
  for (int i = 0; i < 4; ++i) {
#pragma unroll
    for (int r = 0; r < 4; ++r) {
      const float xs = xsq[rowBase + wm * 64 + i * 16 + q * 4 + r];
#pragma unroll
      for (int j = 0; j < 4; ++j)
        patch[(q * 4 + r) * 64 + j * 16 + c] = __expf(acc[i][j][r] - 0.5f * (xs + ms[j]));
    }
    // coalesced read-back: lane l -> dwords 4l..4l+3 (conflict-free); plain
    // (L2-buffered) 1 KiB stores per instruction
#pragma unroll
    for (int r2 = 0; r2 < 4; ++r2) {
      const floatx4 v = *reinterpret_cast<const floatx4*>(&patch[r2 * 256 + lane * 4]);
      const int row = rowBase + wm * 64 + i * 16 + r2 * 4 + (lane >> 4);
      const int col = colBase + wn * 64 + (lane & 15) * 4;
      *reinterpret_cast<floatx4*>(out + (size_t)row * K_ + col) = v;
    }
  }
}

// ---------------- fallback: fused fp32->bf16 staging (if ws too small) ------
__global__ void gauss_mfma_fused(const float* __restrict__ x, const float* __restrict__ mu,
                                 const float* __restrict__ sd,
                                 const float* __restrict__ xsq, const float* __restrict__ musq,
                                 float* __restrict__ out) {
  constexpr int BM = 128, BN = 128, BK = 32;
  __shared__ __align__(16) unsigned short As[BM * BK];
  __shared__ __align__(16) unsigned short Bs[BN * BK];
  __shared__ float invs[D_];
  const int tid = threadIdx.x;
  invs[tid] = 1.0f / sd[tid];
  const int wave = tid >> 6, lane = tid & 63;
  const int wm = wave >> 1, wn = wave & 1;
  const int rowBase = blockIdx.y * BM;
  const int colBase = blockIdx.x * BN;
  const int srow = tid >> 1;
  const int scol = (tid & 1) * 16;
  const float* gA = x + (size_t)(rowBase + srow) * D_ + scol;
  const float* gB = mu + (size_t)(colBase + srow) * (NC_ * D_) + scol;
  __syncthreads();

  floatx4 acc[4][4] = {};
  const int fr = lane & 15;
  const int fk = (lane >> 4) * 8;

  for (int kt = 0; kt < D_ / BK; ++kt) {
    const int k0 = kt * BK;
    float4 a0 = *(const float4*)(gA + k0);
    float4 a1 = *(const float4*)(gA + k0 + 4);
    float4 a2 = *(const float4*)(gA + k0 + 8);
    float4 a3 = *(const float4*)(gA + k0 + 12);
    float4 b0 = *(const float4*)(gB + k0);
    float4 b1 = *(const float4*)(gB + k0 + 4);
    float4 b2 = *(const float4*)(gB + k0 + 8);
    float4 b3 = *(const float4*)(gB + k0 + 12);
    float fa[16] = {a0.x, a0.y, a0.z, a0.w, a1.x, a1.y, a1.z, a1.w,
                    a2.x, a2.y, a2.z, a2.w, a3.x, a3.y, a3.z, a3.w};
    float fb[16] = {b0.x, b0.y, b0.z, b0.w, b1.x, b1.y, b1.z, b1.w,
                    b2.x, b2.y, b2.z, b2.w, b3.x, b3.y, b3.z, b3.w};
    union { unsigned short u[8]; uint4 v; } pa0, pa1, pb0, pb1;
#pragma unroll
    for (int t = 0; t < 8; ++t) {
      pa0.u[t] = f2bf(fa[t]);
      pa1.u[t] = f2bf(fa[t + 8]);
      pb0.u[t] = f2bf(fb[t] * invs[k0 + scol + t]);
      pb1.u[t] = f2bf(fb[t + 8] * invs[k0 + scol + t + 8]);
    }
    __syncthreads();
    *(uint4*)&As[srow * BK + scol]     = pa0.v;
    *(uint4*)&As[srow * BK + scol + 8] = pa1.v;
    *(uint4*)&Bs[srow * BK + scol]     = pb0.v;
    *(uint4*)&Bs[srow * BK + scol + 8] = pb1.v;
    __syncthreads();
    bf16x8 af[4], bfv[4];
#pragma unroll
    for (int i = 0; i < 4; ++i)
      af[i] = *reinterpret_cast<const bf16x8*>(&As[(wm * 64 + i * 16 + fr) * BK + fk]);
#pragma unroll
    for (int j = 0; j < 4; ++j)
      bfv[j] = *reinterpret_cast<const bf16x8*>(&Bs[(wn * 64 + j * 16 + fr) * BK + fk]);
#pragma unroll
    for (int i = 0; i < 4; ++i)
#pragma unroll
      for (int j = 0; j < 4; ++j)
        acc[i][j] = __builtin_amdgcn_mfma_f32_16x16x32_bf16(af[i], bfv[j], acc[i][j], 0, 0, 0);
  }

  const int q = lane >> 4, c = lane & 15;
  float ms[4];
#pragma unroll
  for (int j = 0; j < 4; ++j) ms[j] = musq[colBase + wn * 64 + j * 16 + c];
#pragma unroll
  for (int i = 0; i < 4; ++i) {
#pragma unroll
    for (int r = 0; r < 4; ++r) {
      const int row = rowBase + wm * 64 + i * 16 + q * 4 + r;
      const float xs = xsq[row];
      float* orow = out + (size_t)row * K_ + colBase + wn * 64 + c;
#pragma unroll
      for (int j = 0; j < 4; ++j)
        orow[j * 16] = __expf(acc[i][j][r] - 0.5f * (xs + ms[j]));
    }
  }
}

// ---------------- last-resort naive (no workspace at all) -------------------
__global__ void gauss_naive(const float* __restrict__ x, const float* __restrict__ mu,
                            const float* __restrict__ sd, float* __restrict__ out) {
  const int k = blockIdx.x * 256 + threadIdx.x;
  const int n = blockIdx.y;
  const float* xr = x + (size_t)n * D_;
  const float* mr = mu + (size_t)k * (NC_ * D_);
  float s = 0.0f;
  for (int d = 0; d < D_; ++d) {
    const float diff = xr[d] - mr[d];
    s += diff * diff / sd[d];
  }
  out[(size_t)n * K_ + k] = __expf(-0.5f * s);
}

extern "C" void kernel_launch(void* const* d_in, const int* in_sizes, int n_in,
                              void* d_out, int out_size, void* d_ws, size_t ws_size,
                              hipStream_t stream) {
  const float* x  = (const float*)d_in[0];
  const float* mu = (const float*)d_in[1];
  const float* sd = (const float*)d_in[2];
  float* out = (float*)d_out;

  const size_t xb_bytes   = (size_t)N_ * D_ * 2;  // 16 MiB
  const size_t bb_bytes   = (size_t)K_ * D_ * 2;  //  2 MiB
  const size_t xsq_bytes  = (size_t)N_ * 4;       // 128 KiB
  const size_t musq_bytes = (size_t)K_ * 4;       //  16 KiB

  if (ws_size >= xb_bytes + bb_bytes + xsq_bytes + musq_bytes) {
    unsigned short* xb = (unsigned short*)d_ws;
    unsigned short* bb = (unsigned short*)((char*)d_ws + xb_bytes);
    float* xsq  = (float*)((char*)d_ws + xb_bytes + bb_bytes);
    float* musq = (float*)((char*)d_ws + xb_bytes + bb_bytes + xsq_bytes);
    prep_x_kern<true><<<N_ / 4, 256, 0, stream>>>(x, sd, xb, xsq);
    prep_mu_kern<true><<<K_ / 4, 256, 0, stream>>>(mu, sd, bb, musq);
    gauss_mfma<<<(N_ / 128) * (K_ / 128), 256, 0, stream>>>(xb, bb, xsq, musq, out);
  } else if (ws_size >= xsq_bytes + musq_bytes) {
    float* xsq  = (float*)d_ws;
    float* musq = (float*)((char*)d_ws + xsq_bytes);
    prep_x_kern<false><<<N_ / 4, 256, 0, stream>>>(x, sd, nullptr, xsq);
    prep_mu_kern<false><<<K_ / 4, 256, 0, stream>>>(mu, sd, nullptr, musq);
    gauss_mfma_fused<<<dim3(K_ / 128, N_ / 128), 256, 0, stream>>>(x, mu, sd, xsq, musq, out);
  } else {
    gauss_naive<<<dim3(K_ / 256, N_), 256, 0, stream>>>(x, mu, sd, out);
  }
}

// Round 8
// 578.373 us; speedup vs baseline: 1.1083x; 1.1083x over previous
//
#include <hip/hip_runtime.h>

#define N_ 32768
#define K_ 4096
#define NC_ 4
#define D_ 256

using floatx4 = __attribute__((ext_vector_type(4))) float;
using bf16x8  = __attribute__((ext_vector_type(8))) short;

__device__ __forceinline__ unsigned short f2bf(float f) {
  union { float f; unsigned u; } a;
  a.f = f;
  unsigned u = a.u;
  u += 0x7fffu + ((u >> 16) & 1u);  // round-to-nearest-even
  return (unsigned short)(u >> 16);
}

__device__ __forceinline__ void async_copy16(void* lds, const void* g) {
  __builtin_amdgcn_global_load_lds(
      (__attribute__((address_space(1))) void*)(g),
      (__attribute__((address_space(3))) void*)(lds),
      16, 0, 0);
}

// ---------------- prep kernels: bf16 conversion + weighted row norms --------
template <bool WRITE_BF>
__global__ void prep_x_kern(const float* __restrict__ x, const float* __restrict__ sd,
                            unsigned short* __restrict__ xb, float* __restrict__ xsq) {
  const int lane = threadIdx.x & 63;
  const int row  = blockIdx.x * 4 + (threadIdx.x >> 6);
  const float4 xv = reinterpret_cast<const float4*>(x + (size_t)row * D_)[lane];
  const float4 sv = reinterpret_cast<const float4*>(sd)[lane];
  const float i0 = 1.0f / sv.x, i1 = 1.0f / sv.y, i2 = 1.0f / sv.z, i3 = 1.0f / sv.w;
  float s = xv.x * xv.x * i0 + xv.y * xv.y * i1 + xv.z * xv.z * i2 + xv.w * xv.w * i3;
  if (WRITE_BF) {
    union { unsigned short u[4]; uint2 v; } p;
    p.u[0] = f2bf(xv.x); p.u[1] = f2bf(xv.y); p.u[2] = f2bf(xv.z); p.u[3] = f2bf(xv.w);
    reinterpret_cast<uint2*>(xb)[(size_t)row * 64 + lane] = p.v;
  }
#pragma unroll
  for (int off = 32; off > 0; off >>= 1) s += __shfl_down(s, off, 64);
  if (lane == 0) xsq[row] = s;
}

template <bool WRITE_BF>
__global__ void prep_mu_kern(const float* __restrict__ mu, const float* __restrict__ sd,
                             unsigned short* __restrict__ bb, float* __restrict__ musq) {
  const int lane = threadIdx.x & 63;
  const int row  = blockIdx.x * 4 + (threadIdx.x >> 6);
  const float4 mv = reinterpret_cast<const float4*>(mu + (size_t)row * (NC_ * D_))[lane];
  const float4 sv = reinterpret_cast<const float4*>(sd)[lane];
  const float i0 = 1.0f / sv.x, i1 = 1.0f / sv.y, i2 = 1.0f / sv.z, i3 = 1.0f / sv.w;
  float s = mv.x * mv.x * i0 + mv.y * mv.y * i1 + mv.z * mv.z * i2 + mv.w * mv.w * i3;
  if (WRITE_BF) {
    union { unsigned short u[4]; uint2 v; } p;
    p.u[0] = f2bf(mv.x * i0); p.u[1] = f2bf(mv.y * i1);
    p.u[2] = f2bf(mv.z * i2); p.u[3] = f2bf(mv.w * i3);
    reinterpret_cast<uint2*>(bb)[(size_t)row * 64 + lane] = p.v;
  }
#pragma unroll
  for (int off = 32; off > 0; off >>= 1) s += __shfl_down(s, off, 64);
  if (lane == 0) musq[row] = s;
}

// ---------------- main MFMA GEMM, col-fast swizzle + NT coalesced epilogue --
// C[n,k] = expf( x·b^T - 0.5*(xsq[n] + musq[k]) ),  b = mu0 * inv_std (bf16)
// R8 swizzle: colT fast-varying. 32 consecutive blocks per XCD cover one
// 128-row x 4096-col output band -> concurrent writes form a dense contiguous
// 2 MiB window (DRAM page-friendly), and those 32 blocks share one A-tile.
__global__ __launch_bounds__(256, 3) void gauss_mfma(
    const unsigned short* __restrict__ xb, const unsigned short* __restrict__ bb,
    const float* __restrict__ xsq, const float* __restrict__ musq,
    float* __restrict__ out) {
  constexpr int BM = 128, BN = 128, BK = 32;
  // single contiguous buffer: K-loop uses it as As|Bs; epilogue reuses it as
  // four 4 KiB per-wave transpose patches (16 KiB total).
  __shared__ __align__(16) unsigned short smem[BM * BK + BN * BK];
  unsigned short* As = smem;
  unsigned short* Bs = smem + BM * BK;
  const int tid  = threadIdx.x;
  const int wave = tid >> 6, lane = tid & 63;
  const int wm = wave >> 1, wn = wave & 1;  // 2x2 waves, each 64x64

  const int b   = blockIdx.x;
  const int xcd = b & 7;                    // dispatch round-robins XCDs
  const int g   = b >> 3;                   // 0..1023
  const int colT = g & 31;                  // FAST: consecutive blocks -> cols
  const int rowT = (xcd << 5) | (g >> 5);   // band index, XCD-banded
  const int rowBase = rowT * BM;
  const int colBase = colT * BN;

  // staging: global_load_lds, lds dst = wave-uniform base + lane*16B
  const int srow = lane >> 2;
  const int scol = (lane & 3) * 8;
  const unsigned short* gA0 = xb + (size_t)(rowBase + wave * 16 + srow) * D_ + scol;
  const unsigned short* gA1 = gA0 + (size_t)64 * D_;
  const unsigned short* gB0 = bb + (size_t)(colBase + wave * 16 + srow) * D_ + scol;
  const unsigned short* gB1 = gB0 + (size_t)64 * D_;
  unsigned short* lA0 = &As[(wave * 16) * BK];
  unsigned short* lA1 = &As[(wave * 16 + 64) * BK];
  unsigned short* lB0 = &Bs[(wave * 16) * BK];
  unsigned short* lB1 = &Bs[(wave * 16 + 64) * BK];

  floatx4 acc[4][4] = {};
  const int fr = lane & 15;        // A: row m / B: col n
  const int fk = (lane >> 4) * 8;  // k-chunk (8 contiguous bf16 = 16B)

#pragma unroll
  for (int kt = 0; kt < D_ / BK; ++kt) {
    __syncthreads();  // everyone done reading previous tile
    async_copy16(lA0, gA0 + kt * BK);
    async_copy16(lA1, gA1 + kt * BK);
    async_copy16(lB0, gB0 + kt * BK);
    async_copy16(lB1, gB1 + kt * BK);
    __syncthreads();  // compiler drains vmcnt(0) before s_barrier
    bf16x8 af[4], bfv[4];
#pragma unroll
    for (int i = 0; i < 4; ++i)
      af[i] = *reinterpret_cast<const bf16x8*>(&As[(wm * 64 + i * 16 + fr) * BK + fk]);
#pragma unroll
    for (int j = 0; j < 4; ++j)
      bfv[j] = *reinterpret_cast<const bf16x8*>(&Bs[(wn * 64 + j * 16 + fr) * BK + fk]);
#pragma unroll
    for (int i = 0; i < 4; ++i)
#pragma unroll
      for (int j = 0; j < 4; ++j)
        acc[i][j] = __builtin_amdgcn_mfma_f32_16x16x32_bf16(af[i], bfv[j], acc[i][j], 0, 0, 0);
  }

  // ---- epilogue: exp + per-wave LDS transpose -> contiguous 1 KiB NT stores
  // C/D layout: col=lane&15, row=(lane>>4)*4+reg.
  __syncthreads();  // all waves done with As/Bs before reuse as patches
  float* patch = reinterpret_cast<float*>(smem) + wave * 1024;  // 16 rows x 64 cols
  const int q = lane >> 4, c = lane & 15;
  float ms[4];
#pragma unroll
  for (int j = 0; j < 4; ++j) ms[j] = musq[colBase + wn * 64 + j * 16 + c];

#pragma unroll
  for (int i = 0; i < 4; ++i) {
#pragma unroll
    for (int r = 0; r < 4; ++r) {
      const float xs = xsq[rowBase + wm * 64 + i * 16 + q * 4 + r];
#pragma unroll
      for (int j = 0; j < 4; ++j)
        patch[(q * 4 + r) * 64 + j * 16 + c] = __expf(acc[i][j][r] - 0.5f * (xs + ms[j]));
    }
    // coalesced read-back: lane l -> dwords 4l..4l+3 (conflict-free); NT
    // 1 KiB-per-instruction stores (4 rows x 256 B, full 128 B lines)
#pragma unroll
    for (int r2 = 0; r2 < 4; ++r2) {
      const floatx4 v = *reinterpret_cast<const floatx4*>(&patch[r2 * 256 + lane * 4]);
      const int row = rowBase + wm * 64 + i * 16 + r2 * 4 + (lane >> 4);
      const int col = colBase + wn * 64 + (lane & 15) * 4;
      __builtin_nontemporal_store(v, reinterpret_cast<floatx4*>(out + (size_t)row * K_ + col));
    }
  }
}

// ---------------- fallback: fused fp32->bf16 staging (if ws too small) ------
__global__ void gauss_mfma_fused(const float* __restrict__ x, const float* __restrict__ mu,
                                 const float* __restrict__ sd,
                                 const float* __restrict__ xsq, const float* __restrict__ musq,
                                 float* __restrict__ out) {
  constexpr int BM = 128, BN = 128, BK = 32;
  __shared__ __align__(16) unsigned short As[BM * BK];
  __shared__ __align__(16) unsigned short Bs[BN * BK];
  __shared__ float invs[D_];
  const int tid = threadIdx.x;
  invs[tid] = 1.0f / sd[tid];
  const int wave = tid >> 6, lane = tid & 63;
  const int wm = wave >> 1, wn = wave & 1;
  const int rowBase = blockIdx.y * BM;
  const int colBase = blockIdx.x * BN;
  const int srow = tid >> 1;
  const int scol = (tid & 1) * 16;
  const float* gA = x + (size_t)(rowBase + srow) * D_ + scol;
  const float* gB = mu + (size_t)(colBase + srow) * (NC_ * D_) + scol;
  __syncthreads();

  floatx4 acc[4][4] = {};
  const int fr = lane & 15;
  const int fk = (lane >> 4) * 8;

  for (int kt = 0; kt < D_ / BK; ++kt) {
    const int k0 = kt * BK;
    float4 a0 = *(const float4*)(gA + k0);
    float4 a1 = *(const float4*)(gA + k0 + 4);
    float4 a2 = *(const float4*)(gA + k0 + 8);
    float4 a3 = *(const float4*)(gA + k0 + 12);
    float4 b0 = *(const float4*)(gB + k0);
    float4 b1 = *(const float4*)(gB + k0 + 4);
    float4 b2 = *(const float4*)(gB + k0 + 8);
    float4 b3 = *(const float4*)(gB + k0 + 12);
    float fa[16] = {a0.x, a0.y, a0.z, a0.w, a1.x, a1.y, a1.z, a1.w,
                    a2.x, a2.y, a2.z, a2.w, a3.x, a3.y, a3.z, a3.w};
    float fb[16] = {b0.x, b0.y, b0.z, b0.w, b1.x, b1.y, b1.z, b1.w,
                    b2.x, b2.y, b2.z, b2.w, b3.x, b3.y, b3.z, b3.w};
    union { unsigned short u[8]; uint4 v; } pa0, pa1, pb0, pb1;
#pragma unroll
    for (int t = 0; t < 8; ++t) {
      pa0.u[t] = f2bf(fa[t]);
      pa1.u[t] = f2bf(fa[t + 8]);
      pb0.u[t] = f2bf(fb[t] * invs[k0 + scol + t]);
      pb1.u[t] = f2bf(fb[t + 8] * invs[k0 + scol + t + 8]);
    }
    __syncthreads();
    *(uint4*)&As[srow * BK + scol]     = pa0.v;
    *(uint4*)&As[srow * BK + scol + 8] = pa1.v;
    *(uint4*)&Bs[srow * BK + scol]     = pb0.v;
    *(uint4*)&Bs[srow * BK + scol + 8] = pb1.v;
    __syncthreads();
    bf16x8 af[4], bfv[4];
#pragma unroll
    for (int i = 0; i < 4; ++i)
      af[i] = *reinterpret_cast<const bf16x8*>(&As[(wm * 64 + i * 16 + fr) * BK + fk]);
#pragma unroll
    for (int j = 0; j < 4; ++j)
      bfv[j] = *reinterpret_cast<const bf16x8*>(&Bs[(wn * 64 + j * 16 + fr) * BK + fk]);
#pragma unroll
    for (int i = 0; i < 4; ++i)
#pragma unroll
      for (int j = 0; j < 4; ++j)
        acc[i][j] = __builtin_amdgcn_mfma_f32_16x16x32_bf16(af[i], bfv[j], acc[i][j], 0, 0, 0);
  }

  const int q = lane >> 4, c = lane & 15;
  float ms[4];
#pragma unroll
  for (int j = 0; j < 4; ++j) ms[j] = musq[colBase + wn * 64 + j * 16 + c];
#pragma unroll
  for (int i = 0; i < 4; ++i) {
#pragma unroll
    for (int r = 0; r < 4; ++r) {
      const int row = rowBase + wm * 64 + i * 16 + q * 4 + r;
      const float xs = xsq[row];
      float* orow = out + (size_t)row * K_ + colBase + wn * 64 + c;
#pragma unroll
      for (int j = 0; j < 4; ++j)
        orow[j * 16] = __expf(acc[i][j][r] - 0.5f * (xs + ms[j]));
    }
  }
}

// ---------------- last-resort naive (no workspace at all) -------------------
__global__ void gauss_naive(const float* __restrict__ x, const float* __restrict__ mu,
                            const float* __restrict__ sd, float* __restrict__ out) {
  const int k = blockIdx.x * 256 + threadIdx.x;
  const int n = blockIdx.y;
  const float* xr = x + (size_t)n * D_;
  const float* mr = mu + (size_t)k * (NC_ * D_);
  float s = 0.0f;
  for (int d = 0; d < D_; ++d) {
    const float diff = xr[d] - mr[d];
    s += diff * diff / sd[d];
  }
  out[(size_t)n * K_ + k] = __expf(-0.5f * s);
}

extern "C" void kernel_launch(void* const* d_in, const int* in_sizes, int n_in,
                              void* d_out, int out_size, void* d_ws, size_t ws_size,
                              hipStream_t stream) {
  const float* x  = (const float*)d_in[0];
  const float* mu = (const float*)d_in[1];
  const float* sd = (const float*)d_in[2];
  float* out = (float*)d_out;

  const size_t xb_bytes   = (size_t)N_ * D_ * 2;  // 16 MiB
  const size_t bb_bytes   = (size_t)K_ * D_ * 2;  //  2 MiB
  const size_t xsq_bytes  = (size_t)N_ * 4;       // 128 KiB
  const size_t musq_bytes = (size_t)K_ * 4;       //  16 KiB

  if (ws_size >= xb_bytes + bb_bytes + xsq_bytes + musq_bytes) {
    unsigned short* xb = (unsigned short*)d_ws;
    unsigned short* bb = (unsigned short*)((char*)d_ws + xb_bytes);
    float* xsq  = (float*)((char*)d_ws + xb_bytes + bb_bytes);
    float* musq = (float*)((char*)d_ws + xb_bytes + bb_bytes + xsq_bytes);
    prep_x_kern<true><<<N_ / 4, 256, 0, stream>>>(x, sd, xb, xsq);
    prep_mu_kern<true><<<K_ / 4, 256, 0, stream>>>(mu, sd, bb, musq);
    gauss_mfma<<<(N_ / 128) * (K_ / 128), 256, 0, stream>>>(xb, bb, xsq, musq, out);
  } else if (ws_size >= xsq_bytes + musq_bytes) {
    float* xsq  = (float*)d_ws;
    float* musq = (float*)((char*)d_ws + xsq_bytes);
    prep_x_kern<false><<<N_ / 4, 256, 0, stream>>>(x, sd, nullptr, xsq);
    prep_mu_kern<false><<<K_ / 4, 256, 0, stream>>>(mu, sd, nullptr, musq);
    gauss_mfma_fused<<<dim3(K_ / 128, N_ / 128), 256, 0, stream>>>(x, mu, sd, xsq, musq, out);
  } else {
    gauss_naive<<<dim3(K_ / 256, N_), 256, 0, stream>>>(x, mu, sd, out);
  }
}